// Round 1
// baseline (3856.298 us; speedup 1.0000x reference)
//
#include <hip/hip_runtime.h>
#include <hip/hip_bf16.h>
#include <cstddef>
#include <cstdint>

#define MROWS 131072
#define BK 32

// ---------------------------------------------------------------------------
// Tiled f32 GEMM: C[M,N] = act(A[M,K] @ W[K,N] + bias), optional ReLU,
// optional fused recon-loss partial reduction (last decoder layer).
// Block = 256 threads. Per-thread tile TM x TN. A staged transposed (k-major)
// in LDS with +4 pad; W staged k-major. TN=8 threads own two float4 halves
// (cols tx*4 and BN/2 + tx*4) so b-fragment ds_read_b128 is conflict-free.
// ---------------------------------------------------------------------------
template<int BM, int BN, int TM, int TN, bool RELU, bool RECON>
__launch_bounds__(256)
__global__ void gemm_kernel(const float* __restrict__ A,
                            const float* __restrict__ W,
                            const float* __restrict__ bias,
                            float* __restrict__ C,
                            int K, int N,
                            const float* __restrict__ Xref,
                            double* __restrict__ recon_partial)
{
    constexpr int TX = BN / TN;
    constexpr int TY = BM / TM;
    static_assert(TX * TY == 256, "block must be 256 threads");
    constexpr int NH = TN / 4;            // number of float4 column sections
    constexpr int SEC = BN / NH;          // column section stride

    __shared__ float As[BK][BM + 4];
    __shared__ float Ws[BK][BN];

    const int t  = threadIdx.x;
    const int tx = t % TX;
    const int ty = t / TX;
    const int m0 = blockIdx.y * BM;
    const int n0 = blockIdx.x * BN;

    float acc[TM][TN];
    #pragma unroll
    for (int i = 0; i < TM; ++i)
        #pragma unroll
        for (int j = 0; j < TN; ++j) acc[i][j] = 0.f;

    for (int kt = 0; kt < K; kt += BK) {
        // stage A tile (BM x BK) -> As[k][m] (transposed)
        #pragma unroll
        for (int i = 0; i < (BM * BK / 4) / 256; ++i) {
            int idx4 = t + i * 256;
            int r  = idx4 / (BK / 4);
            int c4 = idx4 % (BK / 4);
            float4 v = *(const float4*)(A + (size_t)(m0 + r) * K + kt + c4 * 4);
            As[c4 * 4 + 0][r] = v.x;
            As[c4 * 4 + 1][r] = v.y;
            As[c4 * 4 + 2][r] = v.z;
            As[c4 * 4 + 3][r] = v.w;
        }
        // stage W tile (BK x BN) -> Ws[k][n]
        #pragma unroll
        for (int i = 0; i < (BK * BN / 4) / 256; ++i) {
            int idx4 = t + i * 256;
            int r  = idx4 / (BN / 4);
            int c4 = idx4 % (BN / 4);
            *(float4*)&Ws[r][c4 * 4] =
                *(const float4*)(W + (size_t)(kt + r) * N + n0 + c4 * 4);
        }
        __syncthreads();

        #pragma unroll
        for (int k = 0; k < BK; ++k) {
            float a[TM], b[TN];
            #pragma unroll
            for (int i = 0; i < TM; i += 4)
                *(float4*)&a[i] = *(const float4*)&As[k][ty * TM + i];
            #pragma unroll
            for (int h = 0; h < NH; ++h)
                *(float4*)&b[h * 4] = *(const float4*)&Ws[k][h * SEC + tx * 4];
            #pragma unroll
            for (int i = 0; i < TM; ++i)
                #pragma unroll
                for (int j = 0; j < TN; ++j)
                    acc[i][j] = fmaf(a[i], b[j], acc[i][j]);
        }
        __syncthreads();
    }

    // epilogue: bias (+ReLU), optional recon accumulation, store
    float bb[TN];
    #pragma unroll
    for (int h = 0; h < NH; ++h)
        #pragma unroll
        for (int jj = 0; jj < 4; ++jj)
            bb[h * 4 + jj] = bias[n0 + h * SEC + tx * 4 + jj];

    float lsum = 0.f;
    #pragma unroll
    for (int i = 0; i < TM; ++i) {
        size_t row = (size_t)(m0 + ty * TM + i);
        #pragma unroll
        for (int h = 0; h < NH; ++h) {
            float v[4];
            #pragma unroll
            for (int jj = 0; jj < 4; ++jj) {
                float xv = acc[i][h * 4 + jj] + bb[h * 4 + jj];
                if (RELU) xv = fmaxf(xv, 0.f);
                v[jj] = xv;
            }
            size_t col = (size_t)(n0 + h * SEC + tx * 4);
            if (RECON) {
                const float* xr = Xref + row * N + col;
                #pragma unroll
                for (int jj = 0; jj < 4; ++jj) {
                    float d = v[jj] - xr[jj];
                    lsum = fmaf(d, d, lsum);
                }
            }
            *(float4*)(C + row * N + col) = make_float4(v[0], v[1], v[2], v[3]);
        }
    }

    if constexpr (RECON) {
        __shared__ double red[256];
        red[t] = (double)lsum;
        __syncthreads();
        #pragma unroll
        for (int s = 128; s > 0; s >>= 1) {
            if (t < s) red[t] += red[t + s];
            __syncthreads();
        }
        if (t == 0) recon_partial[blockIdx.y * gridDim.x + blockIdx.x] = red[0];
    }
}

// ---------------------------------------------------------------------------
// Residual VQ: one thread per row. res kept in registers; codebook read via
// wave-uniform global addresses (scalarizes to s_load / L1 broadcast);
// e2 per level staged in LDS. Score formula mirrors the reference:
// s = (x2 + e2[k]) - 2*dot ; first-occurrence argmin.
// Outputs: q = sum of selected entries, codes (as float), commit partials.
// ---------------------------------------------------------------------------
__launch_bounds__(256)
__global__ void rq_kernel(const float* __restrict__ z,
                          const float* __restrict__ cb,   // [3][256][32]
                          float* __restrict__ q,          // [B][32]
                          float* __restrict__ codes,      // [B][3] as float
                          double* __restrict__ commit_partial)
{
    const int t = threadIdx.x;
    const size_t row = (size_t)blockIdx.x * 256 + t;
    __shared__ float  e2s[256];
    __shared__ double red[256];

    float res[32], qsum[32];
    #pragma unroll
    for (int d = 0; d < 32; d += 4) {
        float4 v = *(const float4*)(z + row * 32 + d);
        res[d] = v.x; res[d + 1] = v.y; res[d + 2] = v.z; res[d + 3] = v.w;
        qsum[d] = 0.f; qsum[d + 1] = 0.f; qsum[d + 2] = 0.f; qsum[d + 3] = 0.f;
    }

    int code_l[3];
    for (int l = 0; l < 3; ++l) {
        // per-thread e2 of entry t for this level
        float e2v = 0.f;
        {
            const float* e = cb + ((size_t)l * 256 + t) * 32;
            #pragma unroll
            for (int d = 0; d < 32; ++d) e2v = fmaf(e[d], e[d], e2v);
        }
        __syncthreads();          // all done reading previous level's e2s
        e2s[t] = e2v;
        __syncthreads();

        float x2 = 0.f;
        #pragma unroll
        for (int d = 0; d < 32; ++d) x2 = fmaf(res[d], res[d], x2);

        float best = 3.4e38f;
        int bidx = 0;
        const float* cl = cb + (size_t)l * 8192;
        for (int k = 0; k < 256; ++k) {
            float dot = 0.f;
            #pragma unroll
            for (int d = 0; d < 32; ++d)
                dot = fmaf(res[d], cl[k * 32 + d], dot);
            float s = (x2 + e2s[k]) - 2.0f * dot;
            if (s < best) { best = s; bidx = k; }   // strict < => first occurrence
        }
        code_l[l] = bidx;

        const float* e = cl + (size_t)bidx * 32;    // divergent gather
        #pragma unroll
        for (int d = 0; d < 32; ++d) {
            float qv = e[d];
            res[d] -= qv;
            qsum[d] += qv;
        }
    }

    #pragma unroll
    for (int d = 0; d < 32; d += 4)
        *(float4*)(q + row * 32 + d) =
            make_float4(qsum[d], qsum[d + 1], qsum[d + 2], qsum[d + 3]);

    codes[row * 3 + 0] = (float)code_l[0];
    codes[row * 3 + 1] = (float)code_l[1];
    codes[row * 3 + 2] = (float)code_l[2];

    // commit = mean((z - q)^2) = mean(res_final^2)
    float cs = 0.f;
    #pragma unroll
    for (int d = 0; d < 32; ++d) cs = fmaf(res[d], res[d], cs);
    red[t] = (double)cs;
    __syncthreads();
    #pragma unroll
    for (int s = 128; s > 0; s >>= 1) {
        if (t < s) red[t] += red[t + s];
        __syncthreads();
    }
    if (t == 0) commit_partial[blockIdx.x] = red[0];
}

// ---------------------------------------------------------------------------
// Final reduction: loss = recon + 0.25*(commit + code) = recon + 0.5*commit
// ---------------------------------------------------------------------------
__launch_bounds__(256)
__global__ void finalize_kernel(const double* __restrict__ recon_p, int nrecon,
                                const double* __restrict__ commit_p, int ncommit,
                                float* __restrict__ out)   // out[0]=loss, out[1]=recon
{
    __shared__ double red[256];
    const int t = threadIdx.x;

    double rs = 0.0;
    for (int i = t; i < nrecon; i += 256) rs += recon_p[i];
    red[t] = rs;
    __syncthreads();
    for (int s = 128; s > 0; s >>= 1) { if (t < s) red[t] += red[t + s]; __syncthreads(); }
    double recon_total = red[0];
    __syncthreads();

    double cs = 0.0;
    for (int i = t; i < ncommit; i += 256) cs += commit_p[i];
    red[t] = cs;
    __syncthreads();
    for (int s = 128; s > 0; s >>= 1) { if (t < s) red[t] += red[t + s]; __syncthreads(); }

    if (t == 0) {
        double recon  = recon_total / (double)((size_t)MROWS * 768);
        double commit = red[0]      / (double)((size_t)MROWS * 32);
        out[0] = (float)(recon + 0.5 * commit);
        out[1] = (float)recon;
    }
}

// ---------------------------------------------------------------------------
extern "C" void kernel_launch(void* const* d_in, const int* in_sizes, int n_in,
                              void* d_out, int out_size, void* d_ws, size_t ws_size,
                              hipStream_t stream)
{
    const int M = MROWS;
    const float* x = (const float*)d_in[0];
    const float *ew[4], *eb[4], *dw[4], *db[4], *cb;

    if (in_sizes[2] == 512) {
        // dict order: x, ew0, eb0, ew1, eb1, ..., dw0, db0, ..., codebooks
        ew[0] = (const float*)d_in[1];  eb[0] = (const float*)d_in[2];
        ew[1] = (const float*)d_in[3];  eb[1] = (const float*)d_in[4];
        ew[2] = (const float*)d_in[5];  eb[2] = (const float*)d_in[6];
        ew[3] = (const float*)d_in[7];  eb[3] = (const float*)d_in[8];
        dw[0] = (const float*)d_in[9];  db[0] = (const float*)d_in[10];
        dw[1] = (const float*)d_in[11]; db[1] = (const float*)d_in[12];
        dw[2] = (const float*)d_in[13]; db[2] = (const float*)d_in[14];
        dw[3] = (const float*)d_in[15]; db[3] = (const float*)d_in[16];
    } else {
        // signature order: x, ew0..3, eb0..3, dw0..3, db0..3, codebooks
        ew[0] = (const float*)d_in[1];  ew[1] = (const float*)d_in[2];
        ew[2] = (const float*)d_in[3];  ew[3] = (const float*)d_in[4];
        eb[0] = (const float*)d_in[5];  eb[1] = (const float*)d_in[6];
        eb[2] = (const float*)d_in[7];  eb[3] = (const float*)d_in[8];
        dw[0] = (const float*)d_in[9];  dw[1] = (const float*)d_in[10];
        dw[2] = (const float*)d_in[11]; dw[3] = (const float*)d_in[12];
        db[0] = (const float*)d_in[13]; db[1] = (const float*)d_in[14];
        db[2] = (const float*)d_in[15]; db[3] = (const float*)d_in[16];
    }
    cb = (const float*)d_in[17];

    // workspace layout (peak 402.7 MB):
    //   bufA [M*512] : h1 -> h3 -> g1 -> g3
    //   bufB [M*256] : h2 -> z (first M*32), q (next M*32) -> g2
    //   recon partials [6144] doubles, commit partials [512] doubles
    float*  bufA     = (float*)d_ws;
    float*  bufB     = bufA + (size_t)M * 512;
    double* recon_p  = (double*)(bufB + (size_t)M * 256);
    double* commit_p = recon_p + 6144;

    float* h1 = bufA;
    float* h2 = bufB;
    float* h3 = bufA;
    float* z  = bufB;
    float* qb = bufB + (size_t)M * 32;
    float* g1 = bufA;
    float* g2 = bufB;
    float* g3 = bufA;

    float* xh       = (float*)d_out;                 // [M,768]
    float* loss_out = xh + (size_t)M * 768;          // loss, recon
    float* codes    = loss_out + 2;                  // [M,3] as float

    dim3 blk(256);

    // encoder (f32 exact path -> codes depend on this)
    gemm_kernel<128,128,8,8,true ,false><<<dim3(4, M/128), blk, 0, stream>>>(x , ew[0], eb[0], h1, 768, 512, nullptr, nullptr);
    gemm_kernel<128,128,8,8,true ,false><<<dim3(2, M/128), blk, 0, stream>>>(h1, ew[1], eb[1], h2, 512, 256, nullptr, nullptr);
    gemm_kernel<128,128,8,8,true ,false><<<dim3(1, M/128), blk, 0, stream>>>(h2, ew[2], eb[2], h3, 256, 128, nullptr, nullptr);
    gemm_kernel<128, 32,4,4,false,false><<<dim3(1, M/128), blk, 0, stream>>>(h3, ew[3], eb[3], z , 128,  32, nullptr, nullptr);

    // residual VQ
    rq_kernel<<<dim3(M / 256), blk, 0, stream>>>(z, cb, qb, codes, commit_p);

    // decoder
    gemm_kernel<128,128,8,8,true ,false><<<dim3(1, M/128), blk, 0, stream>>>(qb, dw[0], db[0], g1,  32, 128, nullptr, nullptr);
    gemm_kernel<128,128,8,8,true ,false><<<dim3(2, M/128), blk, 0, stream>>>(g1, dw[1], db[1], g2, 128, 256, nullptr, nullptr);
    gemm_kernel<128,128,8,8,true ,false><<<dim3(4, M/128), blk, 0, stream>>>(g2, dw[2], db[2], g3, 256, 512, nullptr, nullptr);
    gemm_kernel<128,128,8,8,false,true ><<<dim3(6, M/128), blk, 0, stream>>>(g3, dw[3], db[3], xh, 512, 768, x, recon_p);

    // losses
    finalize_kernel<<<1, blk, 0, stream>>>(recon_p, 6 * (M / 128), commit_p, M / 256, loss_out);
}